// Round 8
// baseline (3701.785 us; speedup 1.0000x reference)
//
#include <hip/hip_runtime.h>

#define T_SEQ 1024
#define BATCH 64
#define DIN   300
#define DPAD  320
#define HD    256
#define NW    1536   // 2 dirs * 3 gates * 256
#define ROWS  65536  // B*T

typedef _Float16 f16x8 __attribute__((ext_vector_type(8)));
typedef _Float16 h2_t  __attribute__((ext_vector_type(2)));
typedef float    f32x4 __attribute__((ext_vector_type(4)));

__device__ __forceinline__ float dot2f(h2_t a, h2_t b, float c) {
#if __has_builtin(__builtin_amdgcn_fdot2)
    return __builtin_amdgcn_fdot2(a, b, c, false);
#else
    return c + (float)a[0]*(float)b[0] + (float)a[1]*(float)b[1];
#endif
}

// pin a 32-bit value (2 packed f16) into an AGPR / read it back
#define AGPR_W(dst, src) \
    asm volatile("v_accvgpr_write_b32 %0, %1" : "=a"(dst) : "v"(src))
__device__ __forceinline__ int agpr_r(int a) {
    int v;
    asm volatile("v_accvgpr_read_b32 %0, %1" : "=v"(v) : "a"(a));
    return v;
}
__device__ __forceinline__ float dot2i(h2_t h, int wbits, float c) {
    return dot2f(h, __builtin_bit_cast(h2_t, wbits), c);
}

__device__ __forceinline__ float sigmoidf_(float x) { return 1.f/(1.f+__expf(-x)); }
__device__ __forceinline__ float tanhf_(float x)    { return 1.f - 2.f/(__expf(2.f*x)+1.f); }

// ---------------- prep: x -> masked padded f16 [ROWS][DPAD] ----------------
__global__ void prep_x(const float* __restrict__ x, const int* __restrict__ len,
                       _Float16* __restrict__ xh) {
    int r = blockIdx.x, k = threadIdx.x;          // r < 65536, k < 320
    int b = r >> 10, t = r & 1023;
    float v = (k < DIN && t < len[b]) ? x[(size_t)r*DIN + k] : 0.f;
    xh[(size_t)r*DPAD + k] = (_Float16)v;
}

// ------------- prep: weights -> f16 (k-padded), concat biases --------------
__global__ void prep_w(const float* __restrict__ wihf, const float* __restrict__ wihb,
                       const float* __restrict__ bihf, const float* __restrict__ bihb,
                       const float* __restrict__ attw,
                       _Float16* __restrict__ wih, _Float16* __restrict__ attwh,
                       float* __restrict__ bih) {
    int bid = blockIdx.x, tid = threadIdx.x;
    if (bid < NW) {
        const float* src = (bid < 768) ? (wihf + (size_t)bid*DIN)
                                       : (wihb + (size_t)(bid-768)*DIN);
        if (tid < DPAD)
            wih[(size_t)bid*DPAD + tid] = (_Float16)((tid < DIN) ? src[tid] : 0.f);
        if (tid == 0)
            bih[bid] = (bid < 768) ? bihf[bid] : bihb[bid-768];
    } else {
        int n = bid - NW;                          // n < 512, tid < 512
        attwh[(size_t)n*512 + tid] = (_Float16)attw[(size_t)n*512 + tid];
    }
}

// ------- GEMM A: gx[ROWS][1536] = xh @ wih^T + bih   (f16 MFMA) ------------
__global__ __launch_bounds__(256) void gemm_gx(const _Float16* __restrict__ xh,
                                               const _Float16* __restrict__ wih,
                                               const float* __restrict__ bih,
                                               _Float16* __restrict__ gx) {
    int m0 = blockIdx.x * 64, n0 = blockIdx.y * 128;
    __shared__ _Float16 As[64][40];
    __shared__ _Float16 Bs[128][40];
    int tid = threadIdx.x;
    int wave = tid >> 6, lane = tid & 63;
    f32x4 acc[8] = {};
    for (int kt = 0; kt < 10; ++kt) {
        int k0 = kt * 32;
        { // stage A (64 rows x 32 k)
            int r = tid >> 2, ko = (tid & 3) * 8;
            *(f16x8*)&As[r][ko] = *(const f16x8*)&xh[(size_t)(m0+r)*DPAD + k0 + ko];
        }
        { // stage B transposed-as-[n][k] (128 rows x 32 k)
            int r = tid >> 1, ko = (tid & 1) * 16;
            *(f16x8*)&Bs[r][ko]   = *(const f16x8*)&wih[(size_t)(n0+r)*DPAD + k0 + ko];
            *(f16x8*)&Bs[r][ko+8] = *(const f16x8*)&wih[(size_t)(n0+r)*DPAD + k0 + ko + 8];
        }
        __syncthreads();
        int kk = (lane >> 4) * 8;
        f16x8 a = *(const f16x8*)&As[wave*16 + (lane & 15)][kk];
#pragma unroll
        for (int nf = 0; nf < 8; ++nf) {
            f16x8 bfr = *(const f16x8*)&Bs[nf*16 + (lane & 15)][kk];
            acc[nf] = __builtin_amdgcn_mfma_f32_16x16x32_f16(a, bfr, acc[nf], 0, 0, 0);
        }
        __syncthreads();
    }
#pragma unroll
    for (int nf = 0; nf < 8; ++nf) {
        int n = n0 + nf*16 + (lane & 15);
        float bv = bih[n];
#pragma unroll
        for (int r = 0; r < 4; ++r) {
            int m = m0 + wave*16 + (lane >> 4)*4 + r;
            gx[(size_t)m*NW + n] = (_Float16)(acc[nf][r] + bv);
        }
    }
}

// ------------------ GRU recurrence: 128 blocks (b, dir) --------------------
// 1024 threads: j = tid>>2 (output idx), q = tid&3 (K-quarter).
// Register plan (the ONLY config that is fully weight-resident AND 4
// waves/SIMD): 64 V + 64 A per thread x 1024 thr = 131072 dwords = the whole
// CU file.  Gate r (32 h2) in arch VGPRs; gates z,n (64 h2) HARD-PINNED in
// AGPRs (r6/r7: pinning works, scratch-free).  AGPR reads software-pipelined
// one k8-phase ahead (r7: +350us).  hb quarters on 144 B stride: 0 conflicts
// (r4-measured).  4 waves/SIMD now hide ds_read/hazard latency that 2 could
// not (r7 bottleneck).
__global__ void __launch_bounds__(1024)
gru_kernel(
        const float* __restrict__ whhf, const float* __restrict__ whhb,
        const float* __restrict__ bhhf, const float* __restrict__ bhhb,
        const _Float16* __restrict__ gx, _Float16* __restrict__ enc) {
    int bid = blockIdx.x;
    int dir = bid & 1, b = bid >> 1;
    int tid = threadIdx.x;
    int j = tid >> 2;
    int q = tid & 3;
    const float* whh = dir ? whhb : whhf;
    const float* bhh = dir ? bhhb : bhhf;

    // weight rows j (r), 256+j (z), 512+j (n); k in [q*64, q*64+64)
    h2_t wr[32];            // arch VGPRs
    int  wza[32], wna[32];  // AGPR-pinned (bit-packed f16x2)
    {
        const float2* pr = (const float2*)(whh + (size_t)j*HD        + q*64);
        const float2* pz = (const float2*)(whh + (size_t)(HD + j)*HD + q*64);
        const float2* pn = (const float2*)(whh + (size_t)(2*HD+j)*HD + q*64);
#pragma unroll
        for (int k = 0; k < 32; ++k) {
            float2 a = pr[k];
            wr[k] = h2_t{(_Float16)a.x, (_Float16)a.y};
            float2 c = pz[k];
            h2_t z2 = h2_t{(_Float16)c.x, (_Float16)c.y};
            AGPR_W(wza[k], __builtin_bit_cast(int, z2));
            float2 d = pn[k];
            h2_t n2 = h2_t{(_Float16)d.x, (_Float16)d.y};
            AGPR_W(wna[k], __builtin_bit_cast(int, n2));
        }
    }
    // bias folded into q==0 accumulator init
    float brh = (q == 0) ? bhh[j]        : 0.f;
    float bzh = (q == 0) ? bhh[HD + j]   : 0.f;
    float bnh = (q == 0) ? bhh[2*HD + j] : 0.f;

    // [dbuf][quarter][64 h + 8 pad] f16 -> 144 B segment stride:
    // read addr (q,k) = q*144 + k*16 -> dword bank (4q + 4k) % 32, distinct per q.
    __shared__ __align__(16) _Float16 hb[2][4][72];
    {
        _Float16* hz0 = &hb[0][0][0];
        if (tid < 2*4*72) hz0[tid] = (_Float16)0.f;
    }
    float hprev = 0.f;
    __syncthreads();

    const _Float16* gxb = gx + (size_t)b*T_SEQ*NW + dir*768 + j;
    int t = dir ? (T_SEQ - 1) : 0;
    int dt = dir ? -1 : 1;
    const _Float16* gp0 = gxb + (size_t)t*NW;
    float xr = (float)gp0[0], xz = (float)gp0[HD], xn = (float)gp0[2*HD];
    int cur = 0;

    for (int s = 0; s < T_SEQ; ++s) {
        // prefetch next step's gx; waitcnt lands after the dot loop
        float nxr = 0.f, nxz = 0.f, nxn = 0.f;
        if (s + 1 < T_SEQ) {
            const _Float16* gq = gxb + (size_t)(t + dt)*NW;
            nxr = (float)gq[0]; nxz = (float)gq[HD]; nxn = (float)gq[2*HD];
        }

        float ar = brh, az = bzh, an = bnh;
        float ar1 = 0.f, az1 = 0.f, an1 = 0.f;
        const _Float16* hseg = &hb[cur][q][0];

        // AGPR software pipeline: cz*/cn* hold phase-k8 weights, read k8+1
        // during phase k8's dots.
        int cz0 = agpr_r(wza[0]), cz1 = agpr_r(wza[1]),
            cz2 = agpr_r(wza[2]), cz3 = agpr_r(wza[3]);
        int cn0 = agpr_r(wna[0]), cn1 = agpr_r(wna[1]),
            cn2 = agpr_r(wna[2]), cn3 = agpr_r(wna[3]);
#pragma unroll
        for (int k8 = 0; k8 < 8; ++k8) {
            int nz0, nz1, nz2, nz3, nn0, nn1, nn2, nn3;
            if (k8 < 7) {
                nz0 = agpr_r(wza[4*k8+4]); nz1 = agpr_r(wza[4*k8+5]);
                nz2 = agpr_r(wza[4*k8+6]); nz3 = agpr_r(wza[4*k8+7]);
                nn0 = agpr_r(wna[4*k8+4]); nn1 = agpr_r(wna[4*k8+5]);
                nn2 = agpr_r(wna[4*k8+6]); nn3 = agpr_r(wna[4*k8+7]);
            } else {
                nz0 = nz1 = nz2 = nz3 = nn0 = nn1 = nn2 = nn3 = 0;
            }
            f16x8 hv = *(const f16x8*)&hseg[k8*8];
            h2_t a0 = {hv[0], hv[1]}, a1 = {hv[2], hv[3]};
            h2_t a2 = {hv[4], hv[5]}, a3 = {hv[6], hv[7]};
            ar  = dot2f(a0, wr[4*k8+0], ar);  ar1 = dot2f(a1, wr[4*k8+1], ar1);
            ar  = dot2f(a2, wr[4*k8+2], ar);  ar1 = dot2f(a3, wr[4*k8+3], ar1);
            az  = dot2i(a0, cz0, az);         az1 = dot2i(a1, cz1, az1);
            az  = dot2i(a2, cz2, az);         az1 = dot2i(a3, cz3, az1);
            an  = dot2i(a0, cn0, an);         an1 = dot2i(a1, cn1, an1);
            an  = dot2i(a2, cn2, an);         an1 = dot2i(a3, cn3, an1);
            cz0 = nz0; cz1 = nz1; cz2 = nz2; cz3 = nz3;
            cn0 = nn0; cn1 = nn1; cn2 = nn2; cn3 = nn3;
        }
        float hr = ar + ar1, hzv = az + az1, hn = an + an1;
        // combine the four K-quarters (lanes 4j..4j+3 -- same wave)
        hr += __shfl_xor(hr, 1); hzv += __shfl_xor(hzv, 1); hn += __shfl_xor(hn, 1);
        hr += __shfl_xor(hr, 2); hzv += __shfl_xor(hzv, 2); hn += __shfl_xor(hn, 2);

        float r  = sigmoidf_(xr + hr);
        float z  = sigmoidf_(xz + hzv);
        float nn = tanhf_(xn + r * hn);
        float h  = (1.f - z) * nn + z * hprev;   // identical in all 4 quad lanes
        hprev = h;

        // packed h2 write: lane tid&7==0 packs {h_j, h_{j+1}} (partner via xor 4)
        float hpar = __shfl_xor(h, 4);
        if ((tid & 7) == 0) {
            h2_t hp = {(_Float16)h, (_Float16)hpar};
            *(h2_t*)&hb[cur ^ 1][j >> 6][j & 63] = hp;
            *(h2_t*)&enc[((size_t)(b*T_SEQ + t))*512 + dir*HD + j] = hp;
        }
        __syncthreads();
        xr = nxr; xz = nxz; xn = nxn;
        cur ^= 1; t += dt;
    }
}

// ------ GEMM U + fused tanh/ctx epilogue -> logits[ROWS]  (f16 MFMA) -------
__global__ __launch_bounds__(256) void gemm_u(const _Float16* __restrict__ enc,
                                              const _Float16* __restrict__ attwh,
                                              const float* __restrict__ attb,
                                              const float* __restrict__ ctx,
                                              float* __restrict__ logits) {
    int m0 = blockIdx.x * 64;
    __shared__ _Float16 As[64][40];
    __shared__ _Float16 Bs[512][40];
    int tid = threadIdx.x;
    int wave = tid >> 6, lane = tid & 63;
    f32x4 acc[32] = {};
    for (int kt = 0; kt < 16; ++kt) {
        int k0 = kt * 32;
        { // stage A (64 x 32)
            int r = tid >> 2, ko = (tid & 3) * 8;
            *(f16x8*)&As[r][ko] = *(const f16x8*)&enc[(size_t)(m0+r)*512 + k0 + ko];
        }
        { // stage B as [n][k] (512 x 32)
#pragma unroll
            for (int jr = 0; jr < 2; ++jr) {
                int row = tid*2 + jr;
#pragma unroll
                for (int q = 0; q < 4; ++q)
                    *(f16x8*)&Bs[row][q*8] =
                        *(const f16x8*)&attwh[(size_t)row*512 + k0 + q*8];
            }
        }
        __syncthreads();
        int kk = (lane >> 4) * 8;
        f16x8 a = *(const f16x8*)&As[wave*16 + (lane & 15)][kk];
#pragma unroll
        for (int nf = 0; nf < 32; ++nf) {
            f16x8 bfr = *(const f16x8*)&Bs[nf*16 + (lane & 15)][kk];
            acc[nf] = __builtin_amdgcn_mfma_f32_16x16x32_f16(a, bfr, acc[nf], 0, 0, 0);
        }
        __syncthreads();
    }
    // epilogue: tanh(u + b) . ctx, reduce over n
    float rs0 = 0.f, rs1 = 0.f, rs2 = 0.f, rs3 = 0.f;
#pragma unroll
    for (int nf = 0; nf < 32; ++nf) {
        int n = nf*16 + (lane & 15);
        float bv = attb[n], cv = ctx[n];
        rs0 += tanhf_(acc[nf][0] + bv) * cv;
        rs1 += tanhf_(acc[nf][1] + bv) * cv;
        rs2 += tanhf_(acc[nf][2] + bv) * cv;
        rs3 += tanhf_(acc[nf][3] + bv) * cv;
    }
#pragma unroll
    for (int off = 1; off < 16; off <<= 1) {
        rs0 += __shfl_xor(rs0, off);
        rs1 += __shfl_xor(rs1, off);
        rs2 += __shfl_xor(rs2, off);
        rs3 += __shfl_xor(rs3, off);
    }
    if ((lane & 15) == 0) {
        int mb = m0 + wave*16 + (lane >> 4)*4;
        logits[mb + 0] = rs0;
        logits[mb + 1] = rs1;
        logits[mb + 2] = rs2;
        logits[mb + 3] = rs3;
    }
}

// ---------------- masked softmax over T + weighted pooling -----------------
__global__ __launch_bounds__(256) void softmax_pool(const float* __restrict__ logits,
                                                    const _Float16* __restrict__ enc,
                                                    const int* __restrict__ lengths,
                                                    float* __restrict__ out) {
    int b = blockIdx.x, tid = threadIdx.x;
    int len = lengths[b];
    if (len < 1) len = 1;
    if (len > T_SEQ) len = T_SEQ;
    __shared__ float att[T_SEQ];
    __shared__ float red[8];
    const float* lg = logits + (size_t)b*T_SEQ;

    float m = -1e30f;
    for (int t = tid; t < len; t += 256) m = fmaxf(m, lg[t]);
#pragma unroll
    for (int off = 1; off < 64; off <<= 1) m = fmaxf(m, __shfl_xor(m, off));
    if ((tid & 63) == 0) red[tid >> 6] = m;
    __syncthreads();
    m = fmaxf(fmaxf(red[0], red[1]), fmaxf(red[2], red[3]));

    float s = 0.f;
    for (int t = tid; t < len; t += 256) {
        float e = __expf(lg[t] - m);
        att[t] = e;
        s += e;
    }
#pragma unroll
    for (int off = 1; off < 64; off <<= 1) s += __shfl_xor(s, off);
    if ((tid & 63) == 0) red[4 + (tid >> 6)] = s;
    __syncthreads();
    s = red[4] + red[5] + red[6] + red[7];
    float inv = 1.f / s;

    float a0 = 0.f, a1 = 0.f;
    const _Float16* eb = enc + (size_t)b*T_SEQ*512;
    for (int t = 0; t < len; ++t) {
        float w = att[t];
        a0 += w * (float)eb[(size_t)t*512 + tid];
        a1 += w * (float)eb[(size_t)t*512 + 256 + tid];
    }
    out[(size_t)b*512 + tid]       = a0 * inv;
    out[(size_t)b*512 + 256 + tid] = a1 * inv;
}

extern "C" void kernel_launch(void* const* d_in, const int* in_sizes, int n_in,
                              void* d_out, int out_size, void* d_ws, size_t ws_size,
                              hipStream_t stream) {
    const float* x    = (const float*)d_in[0];
    const int*   len  = (const int*)  d_in[1];
    const float* wihf = (const float*)d_in[2];
    const float* whhf = (const float*)d_in[3];
    const float* bihf = (const float*)d_in[4];
    const float* bhhf = (const float*)d_in[5];
    const float* wihb = (const float*)d_in[6];
    const float* whhb = (const float*)d_in[7];
    const float* bihb = (const float*)d_in[8];
    const float* bhhb = (const float*)d_in[9];
    const float* attw = (const float*)d_in[10];
    const float* attb = (const float*)d_in[11];
    const float* ctxv = (const float*)d_in[12];
    float* out = (float*)d_out;

    char* ws = (char*)d_ws;
    size_t off = 0;
    _Float16* xh    = (_Float16*)(ws + off); off += (size_t)ROWS*DPAD*2;
    _Float16* wih   = (_Float16*)(ws + off); off += (size_t)NW*DPAD*2;
    _Float16* attwh = (_Float16*)(ws + off); off += (size_t)512*512*2;
    float*    bih   = (float*)   (ws + off); off += (size_t)NW*4;
    _Float16* gx    = (_Float16*)(ws + off); off += (size_t)ROWS*NW*2;
    _Float16* enc   = (_Float16*)(ws + off); off += (size_t)ROWS*512*2;
    float*    logit = (float*)   (ws + off); off += (size_t)ROWS*4;

    prep_x<<<dim3(ROWS), dim3(DPAD), 0, stream>>>(x, len, xh);
    prep_w<<<dim3(NW + 512), dim3(512), 0, stream>>>(wihf, wihb, bihf, bihb, attw,
                                                     wih, attwh, bih);
    gemm_gx<<<dim3(ROWS/64, NW/128), dim3(256), 0, stream>>>(xh, wih, bih, gx);
    gru_kernel<<<dim3(2*BATCH), dim3(1024), 0, stream>>>(whhf, whhb, bhhf, bhhb, gx, enc);
    gemm_u<<<dim3(ROWS/64), dim3(256), 0, stream>>>(enc, attwh, attb, ctxv, logit);
    softmax_pool<<<dim3(BATCH), dim3(256), 0, stream>>>(logit, enc, len, out);
}

// Round 9
// 2224.291 us; speedup vs baseline: 1.6643x; 1.6643x over previous
//
#include <hip/hip_runtime.h>

#define T_SEQ 1024
#define BATCH 64
#define DIN   300
#define DPAD  320
#define HD    256
#define NW    1536   // 2 dirs * 3 gates * 256
#define ROWS  65536  // B*T

typedef _Float16 f16x8 __attribute__((ext_vector_type(8)));
typedef _Float16 h2_t  __attribute__((ext_vector_type(2)));
typedef float    f32x4 __attribute__((ext_vector_type(4)));

__device__ __forceinline__ float dot2f(h2_t a, h2_t b, float c) {
#if __has_builtin(__builtin_amdgcn_fdot2)
    return __builtin_amdgcn_fdot2(a, b, c, false);
#else
    return c + (float)a[0]*(float)b[0] + (float)a[1]*(float)b[1];
#endif
}
// dword-typed dot2: both operands arrive as packed-f16 dwords, no repack
__device__ __forceinline__ float dot2u(unsigned a, unsigned b, float c) {
    return dot2f(__builtin_bit_cast(h2_t, a), __builtin_bit_cast(h2_t, b), c);
}

// pin a 32-bit value (2 packed f16) into an AGPR / read it back
#define AGPR_W(dst, src) \
    asm volatile("v_accvgpr_write_b32 %0, %1" : "=a"(dst) : "v"(src))
__device__ __forceinline__ unsigned agpr_r(unsigned a) {
    unsigned v;
    asm volatile("v_accvgpr_read_b32 %0, %1" : "=v"(v) : "a"(a));
    return v;
}

__device__ __forceinline__ float sigmoidf_(float x) { return 1.f/(1.f+__expf(-x)); }
__device__ __forceinline__ float tanhf_(float x)    { return 1.f - 2.f/(__expf(2.f*x)+1.f); }

__device__ __forceinline__ unsigned packh2(float x, float y) {
    h2_t p = {(_Float16)x, (_Float16)y};
    return __builtin_bit_cast(unsigned, p);
}

// ---------------- prep: x -> masked padded f16 [ROWS][DPAD] ----------------
__global__ void prep_x(const float* __restrict__ x, const int* __restrict__ len,
                       _Float16* __restrict__ xh) {
    int r = blockIdx.x, k = threadIdx.x;          // r < 65536, k < 320
    int b = r >> 10, t = r & 1023;
    float v = (k < DIN && t < len[b]) ? x[(size_t)r*DIN + k] : 0.f;
    xh[(size_t)r*DPAD + k] = (_Float16)v;
}

// ------------- prep: weights -> f16 (k-padded), concat biases --------------
__global__ void prep_w(const float* __restrict__ wihf, const float* __restrict__ wihb,
                       const float* __restrict__ bihf, const float* __restrict__ bihb,
                       const float* __restrict__ attw,
                       _Float16* __restrict__ wih, _Float16* __restrict__ attwh,
                       float* __restrict__ bih) {
    int bid = blockIdx.x, tid = threadIdx.x;
    if (bid < NW) {
        const float* src = (bid < 768) ? (wihf + (size_t)bid*DIN)
                                       : (wihb + (size_t)(bid-768)*DIN);
        if (tid < DPAD)
            wih[(size_t)bid*DPAD + tid] = (_Float16)((tid < DIN) ? src[tid] : 0.f);
        if (tid == 0)
            bih[bid] = (bid < 768) ? bihf[bid] : bihb[bid-768];
    } else {
        int n = bid - NW;                          // n < 512, tid < 512
        attwh[(size_t)n*512 + tid] = (_Float16)attw[(size_t)n*512 + tid];
    }
}

// ------- GEMM A: gx[ROWS][1536] = xh @ wih^T + bih   (f16 MFMA) ------------
__global__ __launch_bounds__(256) void gemm_gx(const _Float16* __restrict__ xh,
                                               const _Float16* __restrict__ wih,
                                               const float* __restrict__ bih,
                                               _Float16* __restrict__ gx) {
    int m0 = blockIdx.x * 64, n0 = blockIdx.y * 128;
    __shared__ _Float16 As[64][40];
    __shared__ _Float16 Bs[128][40];
    int tid = threadIdx.x;
    int wave = tid >> 6, lane = tid & 63;
    f32x4 acc[8] = {};
    for (int kt = 0; kt < 10; ++kt) {
        int k0 = kt * 32;
        { // stage A (64 rows x 32 k)
            int r = tid >> 2, ko = (tid & 3) * 8;
            *(f16x8*)&As[r][ko] = *(const f16x8*)&xh[(size_t)(m0+r)*DPAD + k0 + ko];
        }
        { // stage B transposed-as-[n][k] (128 rows x 32 k)
            int r = tid >> 1, ko = (tid & 1) * 16;
            *(f16x8*)&Bs[r][ko]   = *(const f16x8*)&wih[(size_t)(n0+r)*DPAD + k0 + ko];
            *(f16x8*)&Bs[r][ko+8] = *(const f16x8*)&wih[(size_t)(n0+r)*DPAD + k0 + ko + 8];
        }
        __syncthreads();
        int kk = (lane >> 4) * 8;
        f16x8 a = *(const f16x8*)&As[wave*16 + (lane & 15)][kk];
#pragma unroll
        for (int nf = 0; nf < 8; ++nf) {
            f16x8 bfr = *(const f16x8*)&Bs[nf*16 + (lane & 15)][kk];
            acc[nf] = __builtin_amdgcn_mfma_f32_16x16x32_f16(a, bfr, acc[nf], 0, 0, 0);
        }
        __syncthreads();
    }
#pragma unroll
    for (int nf = 0; nf < 8; ++nf) {
        int n = n0 + nf*16 + (lane & 15);
        float bv = bih[n];
#pragma unroll
        for (int r = 0; r < 4; ++r) {
            int m = m0 + wave*16 + (lane >> 4)*4 + r;
            gx[(size_t)m*NW + n] = (_Float16)(acc[nf][r] + bv);
        }
    }
}

// ------------------ GRU recurrence: 128 blocks (b, dir) --------------------
// 512 threads: j = tid>>1, half = tid&1 (K-half), 192 dword weights/thread.
// wz+wn pinned in AGPRs (r6-r8: only clean full-residency config = 128V+128A,
// 1 block/CU, 2 waves/SIMD).  r9: all h/weight data handled as packed-f16
// DWORDS (uint4 LDS reads + bit_cast into fdot2) -- r7's f16x8 element
// extracts made the compiler emit pack/perm VALU ops that were ~2x-ing the
// instruction count (busy-CU VALUBusy 74%, 4550 cyc/step vs 1520 floor).
__global__ void __launch_bounds__(512)
gru_kernel(
        const float* __restrict__ whhf, const float* __restrict__ whhb,
        const float* __restrict__ bhhf, const float* __restrict__ bhhb,
        const _Float16* __restrict__ gx, _Float16* __restrict__ enc) {
    int bid = blockIdx.x;
    int dir = bid & 1, b = bid >> 1;
    int tid = threadIdx.x;
    int j = tid >> 1;
    int half = tid & 1;
    const float* whh = dir ? whhb : whhf;
    const float* bhh = dir ? bhhb : bhhf;

    // weight rows j (r), 256+j (z), 512+j (n); k in [half*128, half*128+128)
    unsigned wru[64];            // arch VGPRs (packed f16x2 dwords)
    unsigned wza[64], wna[64];   // AGPR-pinned
    {
        const float2* pr = (const float2*)(whh + (size_t)j*HD        + half*128);
        const float2* pz = (const float2*)(whh + (size_t)(HD + j)*HD + half*128);
        const float2* pn = (const float2*)(whh + (size_t)(2*HD+j)*HD + half*128);
#pragma unroll
        for (int k = 0; k < 64; ++k) {
            float2 a = pr[k];
            wru[k] = packh2(a.x, a.y);
            float2 c = pz[k];
            unsigned zz = packh2(c.x, c.y);
            AGPR_W(wza[k], zz);
            float2 d = pn[k];
            unsigned nn2 = packh2(d.x, d.y);
            AGPR_W(wna[k], nn2);
        }
    }
    // bias folded into half==0 accumulator init
    float brh = half ? 0.f : bhh[j];
    float bzh = half ? 0.f : bhh[HD + j];
    float bnh = half ? 0.f : bhh[2*HD + j];

    // [dbuf][half][128 h + 8 pad] -> half stride 272 B (16B-aligned): the two
    // broadcast base addrs differ by 4 dword-banks -> conflict-free.
    __shared__ __align__(16) _Float16 hbuf[2][2][136];
    {
        _Float16* hz0 = &hbuf[0][0][0];
        if (tid < 2*2*136) hz0[tid] = (_Float16)0.f;
    }
    float hprev = 0.f;
    __syncthreads();

    const _Float16* gxb = gx + (size_t)b*T_SEQ*NW + dir*768 + j;
    int t = dir ? (T_SEQ - 1) : 0;
    int dt = dir ? -1 : 1;
    const _Float16* gp0 = gxb + (size_t)t*NW;
    float xr = (float)gp0[0], xz = (float)gp0[HD], xn = (float)gp0[2*HD];
    int cur = 0;

    for (int s = 0; s < T_SEQ; ++s) {
        // prefetch next step's gx; waitcnt lands after the dot loop
        float nxr = 0.f, nxz = 0.f, nxn = 0.f;
        if (s + 1 < T_SEQ) {
            const _Float16* gq = gxb + (size_t)(t + dt)*NW;
            nxr = (float)gq[0]; nxz = (float)gq[HD]; nxn = (float)gq[2*HD];
        }

        float ar = brh, az = bzh, an = bnh;
        float ar1 = 0.f, az1 = 0.f, an1 = 0.f;
        const uint4* hseg4 = (const uint4*)&hbuf[cur][half][0];

        // AGPR software pipeline: cz*/cn* hold phase-k8 weights, read k8+1
        // during phase k8's dots.
        unsigned cz0 = agpr_r(wza[0]), cz1 = agpr_r(wza[1]),
                 cz2 = agpr_r(wza[2]), cz3 = agpr_r(wza[3]);
        unsigned cn0 = agpr_r(wna[0]), cn1 = agpr_r(wna[1]),
                 cn2 = agpr_r(wna[2]), cn3 = agpr_r(wna[3]);
#pragma unroll
        for (int k8 = 0; k8 < 16; ++k8) {
            unsigned nz0, nz1, nz2, nz3, nn0, nn1, nn2, nn3;
            if (k8 < 15) {
                nz0 = agpr_r(wza[4*k8+4]); nz1 = agpr_r(wza[4*k8+5]);
                nz2 = agpr_r(wza[4*k8+6]); nz3 = agpr_r(wza[4*k8+7]);
                nn0 = agpr_r(wna[4*k8+4]); nn1 = agpr_r(wna[4*k8+5]);
                nn2 = agpr_r(wna[4*k8+6]); nn3 = agpr_r(wna[4*k8+7]);
            } else {
                nz0 = nz1 = nz2 = nz3 = nn0 = nn1 = nn2 = nn3 = 0u;
            }
            uint4 hv = hseg4[k8];
            ar  = dot2u(hv.x, wru[4*k8+0], ar);  ar1 = dot2u(hv.y, wru[4*k8+1], ar1);
            ar  = dot2u(hv.z, wru[4*k8+2], ar);  ar1 = dot2u(hv.w, wru[4*k8+3], ar1);
            az  = dot2u(hv.x, cz0, az);          az1 = dot2u(hv.y, cz1, az1);
            az  = dot2u(hv.z, cz2, az);          az1 = dot2u(hv.w, cz3, az1);
            an  = dot2u(hv.x, cn0, an);          an1 = dot2u(hv.y, cn1, an1);
            an  = dot2u(hv.z, cn2, an);          an1 = dot2u(hv.w, cn3, an1);
            cz0 = nz0; cz1 = nz1; cz2 = nz2; cz3 = nz3;
            cn0 = nn0; cn1 = nn1; cn2 = nn2; cn3 = nn3;
        }
        float hr = ar + ar1, hz = az + az1, hn = an + an1;
        // combine the two K-halves (pair lanes 2j, 2j+1 -- same wave)
        hr += __shfl_xor(hr, 1);
        hz += __shfl_xor(hz, 1);
        hn += __shfl_xor(hn, 1);

        float r  = sigmoidf_(xr + hr);
        float z  = sigmoidf_(xz + hz);
        float nn = tanhf_(xn + r * hn);
        float h  = (1.f - z) * nn + z * hprev;   // identical in both half lanes
        hprev = h;

        // packed h2 writes (dword granularity, conflict-free): thread with
        // (tid&3)==0 packs {h_j, h_{j+1}} via its xor-2 partner
        float hpar = __shfl_xor(h, 2);
        if ((tid & 3) == 0) {
            unsigned hp = packh2(h, hpar);
            *(unsigned*)&hbuf[cur ^ 1][j >> 7][j & 127] = hp;
            *(unsigned*)&enc[((size_t)(b*T_SEQ + t))*512 + dir*HD + j] = hp;
        }
        __syncthreads();
        xr = nxr; xz = nxz; xn = nxn;
        cur ^= 1; t += dt;
    }
}

// ------ GEMM U + fused tanh/ctx epilogue -> logits[ROWS]  (f16 MFMA) -------
__global__ __launch_bounds__(256) void gemm_u(const _Float16* __restrict__ enc,
                                              const _Float16* __restrict__ attwh,
                                              const float* __restrict__ attb,
                                              const float* __restrict__ ctx,
                                              float* __restrict__ logits) {
    int m0 = blockIdx.x * 64;
    __shared__ _Float16 As[64][40];
    __shared__ _Float16 Bs[512][40];
    int tid = threadIdx.x;
    int wave = tid >> 6, lane = tid & 63;
    f32x4 acc[32] = {};
    for (int kt = 0; kt < 16; ++kt) {
        int k0 = kt * 32;
        { // stage A (64 x 32)
            int r = tid >> 2, ko = (tid & 3) * 8;
            *(f16x8*)&As[r][ko] = *(const f16x8*)&enc[(size_t)(m0+r)*512 + k0 + ko];
        }
        { // stage B as [n][k] (512 x 32)
#pragma unroll
            for (int jr = 0; jr < 2; ++jr) {
                int row = tid*2 + jr;
#pragma unroll
                for (int q = 0; q < 4; ++q)
                    *(f16x8*)&Bs[row][q*8] =
                        *(const f16x8*)&attwh[(size_t)row*512 + k0 + q*8];
            }
        }
        __syncthreads();
        int kk = (lane >> 4) * 8;
        f16x8 a = *(const f16x8*)&As[wave*16 + (lane & 15)][kk];
#pragma unroll
        for (int nf = 0; nf < 32; ++nf) {
            f16x8 bfr = *(const f16x8*)&Bs[nf*16 + (lane & 15)][kk];
            acc[nf] = __builtin_amdgcn_mfma_f32_16x16x32_f16(a, bfr, acc[nf], 0, 0, 0);
        }
        __syncthreads();
    }
    // epilogue: tanh(u + b) . ctx, reduce over n
    float rs0 = 0.f, rs1 = 0.f, rs2 = 0.f, rs3 = 0.f;
#pragma unroll
    for (int nf = 0; nf < 32; ++nf) {
        int n = nf*16 + (lane & 15);
        float bv = attb[n], cv = ctx[n];
        rs0 += tanhf_(acc[nf][0] + bv) * cv;
        rs1 += tanhf_(acc[nf][1] + bv) * cv;
        rs2 += tanhf_(acc[nf][2] + bv) * cv;
        rs3 += tanhf_(acc[nf][3] + bv) * cv;
    }
#pragma unroll
    for (int off = 1; off < 16; off <<= 1) {
        rs0 += __shfl_xor(rs0, off);
        rs1 += __shfl_xor(rs1, off);
        rs2 += __shfl_xor(rs2, off);
        rs3 += __shfl_xor(rs3, off);
    }
    if ((lane & 15) == 0) {
        int mb = m0 + wave*16 + (lane >> 4)*4;
        logits[mb + 0] = rs0;
        logits[mb + 1] = rs1;
        logits[mb + 2] = rs2;
        logits[mb + 3] = rs3;
    }
}

// ---------------- masked softmax over T + weighted pooling -----------------
__global__ __launch_bounds__(256) void softmax_pool(const float* __restrict__ logits,
                                                    const _Float16* __restrict__ enc,
                                                    const int* __restrict__ lengths,
                                                    float* __restrict__ out) {
    int b = blockIdx.x, tid = threadIdx.x;
    int len = lengths[b];
    if (len < 1) len = 1;
    if (len > T_SEQ) len = T_SEQ;
    __shared__ float att[T_SEQ];
    __shared__ float red[8];
    const float* lg = logits + (size_t)b*T_SEQ;

    float m = -1e30f;
    for (int t = tid; t < len; t += 256) m = fmaxf(m, lg[t]);
#pragma unroll
    for (int off = 1; off < 64; off <<= 1) m = fmaxf(m, __shfl_xor(m, off));
    if ((tid & 63) == 0) red[tid >> 6] = m;
    __syncthreads();
    m = fmaxf(fmaxf(red[0], red[1]), fmaxf(red[2], red[3]));

    float s = 0.f;
    for (int t = tid; t < len; t += 256) {
        float e = __expf(lg[t] - m);
        att[t] = e;
        s += e;
    }
#pragma unroll
    for (int off = 1; off < 64; off <<= 1) s += __shfl_xor(s, off);
    if ((tid & 63) == 0) red[4 + (tid >> 6)] = s;
    __syncthreads();
    s = red[4] + red[5] + red[6] + red[7];
    float inv = 1.f / s;

    float a0 = 0.f, a1 = 0.f;
    const _Float16* eb = enc + (size_t)b*T_SEQ*512;
    for (int t = 0; t < len; ++t) {
        float w = att[t];
        a0 += w * (float)eb[(size_t)t*512 + tid];
        a1 += w * (float)eb[(size_t)t*512 + 256 + tid];
    }
    out[(size_t)b*512 + tid]       = a0 * inv;
    out[(size_t)b*512 + 256 + tid] = a1 * inv;
}

extern "C" void kernel_launch(void* const* d_in, const int* in_sizes, int n_in,
                              void* d_out, int out_size, void* d_ws, size_t ws_size,
                              hipStream_t stream) {
    const float* x    = (const float*)d_in[0];
    const int*   len  = (const int*)  d_in[1];
    const float* wihf = (const float*)d_in[2];
    const float* whhf = (const float*)d_in[3];
    const float* bihf = (const float*)d_in[4];
    const float* bhhf = (const float*)d_in[5];
    const float* wihb = (const float*)d_in[6];
    const float* whhb = (const float*)d_in[7];
    const float* bihb = (const float*)d_in[8];
    const float* bhhb = (const float*)d_in[9];
    const float* attw = (const float*)d_in[10];
    const float* attb = (const float*)d_in[11];
    const float* ctxv = (const float*)d_in[12];
    float* out = (float*)d_out;

    char* ws = (char*)d_ws;
    size_t off = 0;
    _Float16* xh    = (_Float16*)(ws + off); off += (size_t)ROWS*DPAD*2;
    _Float16* wih   = (_Float16*)(ws + off); off += (size_t)NW*DPAD*2;
    _Float16* attwh = (_Float16*)(ws + off); off += (size_t)512*512*2;
    float*    bih   = (float*)   (ws + off); off += (size_t)NW*4;
    _Float16* gx    = (_Float16*)(ws + off); off += (size_t)ROWS*NW*2;
    _Float16* enc   = (_Float16*)(ws + off); off += (size_t)ROWS*512*2;
    float*    logit = (float*)   (ws + off); off += (size_t)ROWS*4;

    prep_x<<<dim3(ROWS), dim3(DPAD), 0, stream>>>(x, len, xh);
    prep_w<<<dim3(NW + 512), dim3(512), 0, stream>>>(wihf, wihb, bihf, bihb, attw,
                                                     wih, attwh, bih);
    gemm_gx<<<dim3(ROWS/64, NW/128), dim3(256), 0, stream>>>(xh, wih, bih, gx);
    gru_kernel<<<dim3(2*BATCH), dim3(512), 0, stream>>>(whhf, whhb, bhhf, bhhb, gx, enc);
    gemm_u<<<dim3(ROWS/64), dim3(256), 0, stream>>>(enc, attwh, attb, ctxv, logit);
    softmax_pool<<<dim3(BATCH), dim3(256), 0, stream>>>(logit, enc, len, out);
}

// Round 10
// 2179.234 us; speedup vs baseline: 1.6987x; 1.0207x over previous
//
#include <hip/hip_runtime.h>

#define T_SEQ 1024
#define BATCH 64
#define DIN   300
#define DPAD  320
#define HD    256
#define NW    1536   // 2 dirs * 3 gates * 256
#define ROWS  65536  // B*T

typedef _Float16 f16x8 __attribute__((ext_vector_type(8)));
typedef _Float16 h2_t  __attribute__((ext_vector_type(2)));
typedef float    f32x4 __attribute__((ext_vector_type(4)));

__device__ __forceinline__ float dot2f(h2_t a, h2_t b, float c) {
#if __has_builtin(__builtin_amdgcn_fdot2)
    return __builtin_amdgcn_fdot2(a, b, c, false);
#else
    return c + (float)a[0]*(float)b[0] + (float)a[1]*(float)b[1];
#endif
}
// dword-typed dot2: both operands arrive as packed-f16 dwords, no repack
__device__ __forceinline__ float dot2u(unsigned a, unsigned b, float c) {
    return dot2f(__builtin_bit_cast(h2_t, a), __builtin_bit_cast(h2_t, b), c);
}

// pin a 32-bit value (2 packed f16) into an AGPR / read it back.
// WRITE stays volatile (one-time init, must not be elided).  READ is
// NON-volatile: it is a pure value computation (SSA dataflow from the write
// keeps ordering) -- r9's volatile reads were scheduler barriers that
// prevented hoisting the per-phase ds_read_b128, exposing ~70 cyc of LDS
// latency x 16 phases per step with only 2 waves/SIMD to cover it.
#define AGPR_W(dst, src) \
    asm volatile("v_accvgpr_write_b32 %0, %1" : "=a"(dst) : "v"(src))
__device__ __forceinline__ unsigned agpr_r(unsigned a) {
    unsigned v;
    asm("v_accvgpr_read_b32 %0, %1" : "=v"(v) : "a"(a));
    return v;
}

__device__ __forceinline__ float sigmoidf_(float x) { return 1.f/(1.f+__expf(-x)); }
__device__ __forceinline__ float tanhf_(float x)    { return 1.f - 2.f/(__expf(2.f*x)+1.f); }

__device__ __forceinline__ unsigned packh2(float x, float y) {
    h2_t p = {(_Float16)x, (_Float16)y};
    return __builtin_bit_cast(unsigned, p);
}

// ---------------- prep: x -> masked padded f16 [ROWS][DPAD] ----------------
__global__ void prep_x(const float* __restrict__ x, const int* __restrict__ len,
                       _Float16* __restrict__ xh) {
    int r = blockIdx.x, k = threadIdx.x;          // r < 65536, k < 320
    int b = r >> 10, t = r & 1023;
    float v = (k < DIN && t < len[b]) ? x[(size_t)r*DIN + k] : 0.f;
    xh[(size_t)r*DPAD + k] = (_Float16)v;
}

// ------------- prep: weights -> f16 (k-padded), concat biases --------------
__global__ void prep_w(const float* __restrict__ wihf, const float* __restrict__ wihb,
                       const float* __restrict__ bihf, const float* __restrict__ bihb,
                       const float* __restrict__ attw,
                       _Float16* __restrict__ wih, _Float16* __restrict__ attwh,
                       float* __restrict__ bih) {
    int bid = blockIdx.x, tid = threadIdx.x;
    if (bid < NW) {
        const float* src = (bid < 768) ? (wihf + (size_t)bid*DIN)
                                       : (wihb + (size_t)(bid-768)*DIN);
        if (tid < DPAD)
            wih[(size_t)bid*DPAD + tid] = (_Float16)((tid < DIN) ? src[tid] : 0.f);
        if (tid == 0)
            bih[bid] = (bid < 768) ? bihf[bid] : bihb[bid-768];
    } else {
        int n = bid - NW;                          // n < 512, tid < 512
        attwh[(size_t)n*512 + tid] = (_Float16)attw[(size_t)n*512 + tid];
    }
}

// ------- GEMM A: gx[ROWS][1536] = xh @ wih^T + bih   (f16 MFMA) ------------
__global__ __launch_bounds__(256) void gemm_gx(const _Float16* __restrict__ xh,
                                               const _Float16* __restrict__ wih,
                                               const float* __restrict__ bih,
                                               _Float16* __restrict__ gx) {
    int m0 = blockIdx.x * 64, n0 = blockIdx.y * 128;
    __shared__ _Float16 As[64][40];
    __shared__ _Float16 Bs[128][40];
    int tid = threadIdx.x;
    int wave = tid >> 6, lane = tid & 63;
    f32x4 acc[8] = {};
    for (int kt = 0; kt < 10; ++kt) {
        int k0 = kt * 32;
        { // stage A (64 rows x 32 k)
            int r = tid >> 2, ko = (tid & 3) * 8;
            *(f16x8*)&As[r][ko] = *(const f16x8*)&xh[(size_t)(m0+r)*DPAD + k0 + ko];
        }
        { // stage B transposed-as-[n][k] (128 rows x 32 k)
            int r = tid >> 1, ko = (tid & 1) * 16;
            *(f16x8*)&Bs[r][ko]   = *(const f16x8*)&wih[(size_t)(n0+r)*DPAD + k0 + ko];
            *(f16x8*)&Bs[r][ko+8] = *(const f16x8*)&wih[(size_t)(n0+r)*DPAD + k0 + ko + 8];
        }
        __syncthreads();
        int kk = (lane >> 4) * 8;
        f16x8 a = *(const f16x8*)&As[wave*16 + (lane & 15)][kk];
#pragma unroll
        for (int nf = 0; nf < 8; ++nf) {
            f16x8 bfr = *(const f16x8*)&Bs[nf*16 + (lane & 15)][kk];
            acc[nf] = __builtin_amdgcn_mfma_f32_16x16x32_f16(a, bfr, acc[nf], 0, 0, 0);
        }
        __syncthreads();
    }
#pragma unroll
    for (int nf = 0; nf < 8; ++nf) {
        int n = n0 + nf*16 + (lane & 15);
        float bv = bih[n];
#pragma unroll
        for (int r = 0; r < 4; ++r) {
            int m = m0 + wave*16 + (lane >> 4)*4 + r;
            gx[(size_t)m*NW + n] = (_Float16)(acc[nf][r] + bv);
        }
    }
}

// ------------------ GRU recurrence: 128 blocks (b, dir) --------------------
// 512 threads: j = tid>>1, half = tid&1 (K-half), 192 dword weights/thread.
// wz+wn pinned in AGPRs (128V+128A = clean full-residency, 2 waves/SIMD,
// scratch-free, conflict-free).  r10: non-volatile AGPR reads (scheduler can
// interleave + hoist LDS reads) and explicit 2-phase LDS read pipeline.
__global__ void __launch_bounds__(512)
gru_kernel(
        const float* __restrict__ whhf, const float* __restrict__ whhb,
        const float* __restrict__ bhhf, const float* __restrict__ bhhb,
        const _Float16* __restrict__ gx, _Float16* __restrict__ enc) {
    int bid = blockIdx.x;
    int dir = bid & 1, b = bid >> 1;
    int tid = threadIdx.x;
    int j = tid >> 1;
    int half = tid & 1;
    const float* whh = dir ? whhb : whhf;
    const float* bhh = dir ? bhhb : bhhf;

    // weight rows j (r), 256+j (z), 512+j (n); k in [half*128, half*128+128)
    unsigned wru[64];            // arch VGPRs (packed f16x2 dwords)
    unsigned wza[64], wna[64];   // AGPR-pinned
    {
        const float2* pr = (const float2*)(whh + (size_t)j*HD        + half*128);
        const float2* pz = (const float2*)(whh + (size_t)(HD + j)*HD + half*128);
        const float2* pn = (const float2*)(whh + (size_t)(2*HD+j)*HD + half*128);
#pragma unroll
        for (int k = 0; k < 64; ++k) {
            float2 a = pr[k];
            wru[k] = packh2(a.x, a.y);
            float2 c = pz[k];
            unsigned zz = packh2(c.x, c.y);
            AGPR_W(wza[k], zz);
            float2 d = pn[k];
            unsigned nn2 = packh2(d.x, d.y);
            AGPR_W(wna[k], nn2);
        }
    }
    // bias folded into half==0 accumulator init
    float brh = half ? 0.f : bhh[j];
    float bzh = half ? 0.f : bhh[HD + j];
    float bnh = half ? 0.f : bhh[2*HD + j];

    // [dbuf][half][128 h + 8 pad] -> half stride 272 B (16B-aligned): the two
    // broadcast base addrs differ by 4 dword-banks -> conflict-free.
    __shared__ __align__(16) _Float16 hbuf[2][2][136];
    {
        _Float16* hz0 = &hbuf[0][0][0];
        if (tid < 2*2*136) hz0[tid] = (_Float16)0.f;
    }
    float hprev = 0.f;
    __syncthreads();

    const _Float16* gxb = gx + (size_t)b*T_SEQ*NW + dir*768 + j;
    int t = dir ? (T_SEQ - 1) : 0;
    int dt = dir ? -1 : 1;
    const _Float16* gp0 = gxb + (size_t)t*NW;
    float xr = (float)gp0[0], xz = (float)gp0[HD], xn = (float)gp0[2*HD];
    int cur = 0;

    for (int s = 0; s < T_SEQ; ++s) {
        // prefetch next step's gx; waitcnt lands after the dot loop
        float nxr = 0.f, nxz = 0.f, nxn = 0.f;
        if (s + 1 < T_SEQ) {
            const _Float16* gq = gxb + (size_t)(t + dt)*NW;
            nxr = (float)gq[0]; nxz = (float)gq[HD]; nxn = (float)gq[2*HD];
        }

        float ar = brh, az = bzh, an = bnh;
        float ar1 = 0.f, az1 = 0.f, an1 = 0.f;
        const uint4* hseg4 = (const uint4*)&hbuf[cur][half][0];

        // LDS reads pipelined 2 phases ahead; AGPR reads pipelined 1 phase.
        uint4 hva = hseg4[0], hvb = hseg4[1];
        unsigned cz0 = agpr_r(wza[0]), cz1 = agpr_r(wza[1]),
                 cz2 = agpr_r(wza[2]), cz3 = agpr_r(wza[3]);
        unsigned cn0 = agpr_r(wna[0]), cn1 = agpr_r(wna[1]),
                 cn2 = agpr_r(wna[2]), cn3 = agpr_r(wna[3]);
#pragma unroll
        for (int k8 = 0; k8 < 16; ++k8) {
            uint4 hv = hva;
            hva = hvb;
            hvb = hseg4[(k8 + 2) & 15];
            unsigned nz0 = agpr_r(wza[(4*k8+4) & 63]), nz1 = agpr_r(wza[(4*k8+5) & 63]);
            unsigned nz2 = agpr_r(wza[(4*k8+6) & 63]), nz3 = agpr_r(wza[(4*k8+7) & 63]);
            unsigned nn0 = agpr_r(wna[(4*k8+4) & 63]), nn1 = agpr_r(wna[(4*k8+5) & 63]);
            unsigned nn2 = agpr_r(wna[(4*k8+6) & 63]), nn3 = agpr_r(wna[(4*k8+7) & 63]);
            ar  = dot2u(hv.x, wru[4*k8+0], ar);  ar1 = dot2u(hv.y, wru[4*k8+1], ar1);
            ar  = dot2u(hv.z, wru[4*k8+2], ar);  ar1 = dot2u(hv.w, wru[4*k8+3], ar1);
            az  = dot2u(hv.x, cz0, az);          az1 = dot2u(hv.y, cz1, az1);
            az  = dot2u(hv.z, cz2, az);          az1 = dot2u(hv.w, cz3, az1);
            an  = dot2u(hv.x, cn0, an);          an1 = dot2u(hv.y, cn1, an1);
            an  = dot2u(hv.z, cn2, an);          an1 = dot2u(hv.w, cn3, an1);
            cz0 = nz0; cz1 = nz1; cz2 = nz2; cz3 = nz3;
            cn0 = nn0; cn1 = nn1; cn2 = nn2; cn3 = nn3;
        }
        float hr = ar + ar1, hz = az + az1, hn = an + an1;
        // combine the two K-halves (pair lanes 2j, 2j+1 -- same wave)
        hr += __shfl_xor(hr, 1);
        hz += __shfl_xor(hz, 1);
        hn += __shfl_xor(hn, 1);

        float r  = sigmoidf_(xr + hr);
        float z  = sigmoidf_(xz + hz);
        float nn = tanhf_(xn + r * hn);
        float h  = (1.f - z) * nn + z * hprev;   // identical in both half lanes
        hprev = h;

        // packed h2 writes (dword granularity, conflict-free): thread with
        // (tid&3)==0 packs {h_j, h_{j+1}} via its xor-2 partner
        float hpar = __shfl_xor(h, 2);
        if ((tid & 3) == 0) {
            unsigned hp = packh2(h, hpar);
            *(unsigned*)&hbuf[cur ^ 1][j >> 7][j & 127] = hp;
            *(unsigned*)&enc[((size_t)(b*T_SEQ + t))*512 + dir*HD + j] = hp;
        }
        __syncthreads();
        xr = nxr; xz = nxz; xn = nxn;
        cur ^= 1; t += dt;
    }
}

// ------ GEMM U + fused tanh/ctx epilogue -> logits[ROWS]  (f16 MFMA) -------
__global__ __launch_bounds__(256) void gemm_u(const _Float16* __restrict__ enc,
                                              const _Float16* __restrict__ attwh,
                                              const float* __restrict__ attb,
                                              const float* __restrict__ ctx,
                                              float* __restrict__ logits) {
    int m0 = blockIdx.x * 64;
    __shared__ _Float16 As[64][40];
    __shared__ _Float16 Bs[512][40];
    int tid = threadIdx.x;
    int wave = tid >> 6, lane = tid & 63;
    f32x4 acc[32] = {};
    for (int kt = 0; kt < 16; ++kt) {
        int k0 = kt * 32;
        { // stage A (64 x 32)
            int r = tid >> 2, ko = (tid & 3) * 8;
            *(f16x8*)&As[r][ko] = *(const f16x8*)&enc[(size_t)(m0+r)*512 + k0 + ko];
        }
        { // stage B as [n][k] (512 x 32)
#pragma unroll
            for (int jr = 0; jr < 2; ++jr) {
                int row = tid*2 + jr;
#pragma unroll
                for (int q = 0; q < 4; ++q)
                    *(f16x8*)&Bs[row][q*8] =
                        *(const f16x8*)&attwh[(size_t)row*512 + k0 + q*8];
            }
        }
        __syncthreads();
        int kk = (lane >> 4) * 8;
        f16x8 a = *(const f16x8*)&As[wave*16 + (lane & 15)][kk];
#pragma unroll
        for (int nf = 0; nf < 32; ++nf) {
            f16x8 bfr = *(const f16x8*)&Bs[nf*16 + (lane & 15)][kk];
            acc[nf] = __builtin_amdgcn_mfma_f32_16x16x32_f16(a, bfr, acc[nf], 0, 0, 0);
        }
        __syncthreads();
    }
    // epilogue: tanh(u + b) . ctx, reduce over n
    float rs0 = 0.f, rs1 = 0.f, rs2 = 0.f, rs3 = 0.f;
#pragma unroll
    for (int nf = 0; nf < 32; ++nf) {
        int n = nf*16 + (lane & 15);
        float bv = attb[n], cv = ctx[n];
        rs0 += tanhf_(acc[nf][0] + bv) * cv;
        rs1 += tanhf_(acc[nf][1] + bv) * cv;
        rs2 += tanhf_(acc[nf][2] + bv) * cv;
        rs3 += tanhf_(acc[nf][3] + bv) * cv;
    }
#pragma unroll
    for (int off = 1; off < 16; off <<= 1) {
        rs0 += __shfl_xor(rs0, off);
        rs1 += __shfl_xor(rs1, off);
        rs2 += __shfl_xor(rs2, off);
        rs3 += __shfl_xor(rs3, off);
    }
    if ((lane & 15) == 0) {
        int mb = m0 + wave*16 + (lane >> 4)*4;
        logits[mb + 0] = rs0;
        logits[mb + 1] = rs1;
        logits[mb + 2] = rs2;
        logits[mb + 3] = rs3;
    }
}

// ---------------- masked softmax over T + weighted pooling -----------------
__global__ __launch_bounds__(256) void softmax_pool(const float* __restrict__ logits,
                                                    const _Float16* __restrict__ enc,
                                                    const int* __restrict__ lengths,
                                                    float* __restrict__ out) {
    int b = blockIdx.x, tid = threadIdx.x;
    int len = lengths[b];
    if (len < 1) len = 1;
    if (len > T_SEQ) len = T_SEQ;
    __shared__ float att[T_SEQ];
    __shared__ float red[8];
    const float* lg = logits + (size_t)b*T_SEQ;

    float m = -1e30f;
    for (int t = tid; t < len; t += 256) m = fmaxf(m, lg[t]);
#pragma unroll
    for (int off = 1; off < 64; off <<= 1) m = fmaxf(m, __shfl_xor(m, off));
    if ((tid & 63) == 0) red[tid >> 6] = m;
    __syncthreads();
    m = fmaxf(fmaxf(red[0], red[1]), fmaxf(red[2], red[3]));

    float s = 0.f;
    for (int t = tid; t < len; t += 256) {
        float e = __expf(lg[t] - m);
        att[t] = e;
        s += e;
    }
#pragma unroll
    for (int off = 1; off < 64; off <<= 1) s += __shfl_xor(s, off);
    if ((tid & 63) == 0) red[4 + (tid >> 6)] = s;
    __syncthreads();
    s = red[4] + red[5] + red[6] + red[7];
    float inv = 1.f / s;

    float a0 = 0.f, a1 = 0.f;
    const _Float16* eb = enc + (size_t)b*T_SEQ*512;
    for (int t = 0; t < len; ++t) {
        float w = att[t];
        a0 += w * (float)eb[(size_t)t*512 + tid];
        a1 += w * (float)eb[(size_t)t*512 + 256 + tid];
    }
    out[(size_t)b*512 + tid]       = a0 * inv;
    out[(size_t)b*512 + 256 + tid] = a1 * inv;
}

extern "C" void kernel_launch(void* const* d_in, const int* in_sizes, int n_in,
                              void* d_out, int out_size, void* d_ws, size_t ws_size,
                              hipStream_t stream) {
    const float* x    = (const float*)d_in[0];
    const int*   len  = (const int*)  d_in[1];
    const float* wihf = (const float*)d_in[2];
    const float* whhf = (const float*)d_in[3];
    const float* bihf = (const float*)d_in[4];
    const float* bhhf = (const float*)d_in[5];
    const float* wihb = (const float*)d_in[6];
    const float* whhb = (const float*)d_in[7];
    const float* bihb = (const float*)d_in[8];
    const float* bhhb = (const float*)d_in[9];
    const float* attw = (const float*)d_in[10];
    const float* attb = (const float*)d_in[11];
    const float* ctxv = (const float*)d_in[12];
    float* out = (float*)d_out;

    char* ws = (char*)d_ws;
    size_t off = 0;
    _Float16* xh    = (_Float16*)(ws + off); off += (size_t)ROWS*DPAD*2;
    _Float16* wih   = (_Float16*)(ws + off); off += (size_t)NW*DPAD*2;
    _Float16* attwh = (_Float16*)(ws + off); off += (size_t)512*512*2;
    float*    bih   = (float*)   (ws + off); off += (size_t)NW*4;
    _Float16* gx    = (_Float16*)(ws + off); off += (size_t)ROWS*NW*2;
    _Float16* enc   = (_Float16*)(ws + off); off += (size_t)ROWS*512*2;
    float*    logit = (float*)   (ws + off); off += (size_t)ROWS*4;

    prep_x<<<dim3(ROWS), dim3(DPAD), 0, stream>>>(x, len, xh);
    prep_w<<<dim3(NW + 512), dim3(512), 0, stream>>>(wihf, wihb, bihf, bihb, attw,
                                                     wih, attwh, bih);
    gemm_gx<<<dim3(ROWS/64, NW/128), dim3(256), 0, stream>>>(xh, wih, bih, gx);
    gru_kernel<<<dim3(2*BATCH), dim3(512), 0, stream>>>(whhf, whhb, bhhf, bhhb, gx, enc);
    gemm_u<<<dim3(ROWS/64), dim3(256), 0, stream>>>(enc, attwh, attb, ctxv, logit);
    softmax_pool<<<dim3(BATCH), dim3(256), 0, stream>>>(logit, enc, len, out);
}

// Round 11
// 1732.309 us; speedup vs baseline: 2.1369x; 1.2580x over previous
//
#include <hip/hip_runtime.h>

#define T_SEQ 1024
#define BATCH 64
#define DIN   300
#define DPAD  320
#define HD    256
#define NW    1536   // 2 dirs * 3 gates * 256
#define ROWS  65536  // B*T

typedef _Float16 f16x8 __attribute__((ext_vector_type(8)));
typedef _Float16 h2_t  __attribute__((ext_vector_type(2)));
typedef float    f32x4 __attribute__((ext_vector_type(4)));

__device__ __forceinline__ float dot2f(h2_t a, h2_t b, float c) {
#if __has_builtin(__builtin_amdgcn_fdot2)
    return __builtin_amdgcn_fdot2(a, b, c, false);
#else
    return c + (float)a[0]*(float)b[0] + (float)a[1]*(float)b[1];
#endif
}
// dword-typed dot2: both operands arrive as packed-f16 dwords, no repack
__device__ __forceinline__ float dot2u(unsigned a, unsigned b, float c) {
    return dot2f(__builtin_bit_cast(h2_t, a), __builtin_bit_cast(h2_t, b), c);
}

__device__ __forceinline__ float sigmoidf_(float x) { return 1.f/(1.f+__expf(-x)); }
__device__ __forceinline__ float tanhf_(float x)    { return 1.f - 2.f/(__expf(2.f*x)+1.f); }

__device__ __forceinline__ unsigned packh2(float x, float y) {
    h2_t p = {(_Float16)x, (_Float16)y};
    return __builtin_bit_cast(unsigned, p);
}

// ---------------- prep: x -> masked padded f16 [ROWS][DPAD] ----------------
__global__ void prep_x(const float* __restrict__ x, const int* __restrict__ len,
                       _Float16* __restrict__ xh) {
    int r = blockIdx.x, k = threadIdx.x;          // r < 65536, k < 320
    int b = r >> 10, t = r & 1023;
    float v = (k < DIN && t < len[b]) ? x[(size_t)r*DIN + k] : 0.f;
    xh[(size_t)r*DPAD + k] = (_Float16)v;
}

// ------------- prep: weights -> f16 (k-padded), concat biases --------------
__global__ void prep_w(const float* __restrict__ wihf, const float* __restrict__ wihb,
                       const float* __restrict__ bihf, const float* __restrict__ bihb,
                       const float* __restrict__ attw,
                       _Float16* __restrict__ wih, _Float16* __restrict__ attwh,
                       float* __restrict__ bih) {
    int bid = blockIdx.x, tid = threadIdx.x;
    if (bid < NW) {
        const float* src = (bid < 768) ? (wihf + (size_t)bid*DIN)
                                       : (wihb + (size_t)(bid-768)*DIN);
        if (tid < DPAD)
            wih[(size_t)bid*DPAD + tid] = (_Float16)((tid < DIN) ? src[tid] : 0.f);
        if (tid == 0)
            bih[bid] = (bid < 768) ? bihf[bid] : bihb[bid-768];
    } else {
        int n = bid - NW;                          // n < 512, tid < 512
        attwh[(size_t)n*512 + tid] = (_Float16)attw[(size_t)n*512 + tid];
    }
}

// ------- GEMM A: gx[ROWS][1536] = xh @ wih^T + bih   (f16 MFMA) ------------
__global__ __launch_bounds__(256) void gemm_gx(const _Float16* __restrict__ xh,
                                               const _Float16* __restrict__ wih,
                                               const float* __restrict__ bih,
                                               _Float16* __restrict__ gx) {
    int m0 = blockIdx.x * 64, n0 = blockIdx.y * 128;
    __shared__ _Float16 As[64][40];
    __shared__ _Float16 Bs[128][40];
    int tid = threadIdx.x;
    int wave = tid >> 6, lane = tid & 63;
    f32x4 acc[8] = {};
    for (int kt = 0; kt < 10; ++kt) {
        int k0 = kt * 32;
        { // stage A (64 rows x 32 k)
            int r = tid >> 2, ko = (tid & 3) * 8;
            *(f16x8*)&As[r][ko] = *(const f16x8*)&xh[(size_t)(m0+r)*DPAD + k0 + ko];
        }
        { // stage B transposed-as-[n][k] (128 rows x 32 k)
            int r = tid >> 1, ko = (tid & 1) * 16;
            *(f16x8*)&Bs[r][ko]   = *(const f16x8*)&wih[(size_t)(n0+r)*DPAD + k0 + ko];
            *(f16x8*)&Bs[r][ko+8] = *(const f16x8*)&wih[(size_t)(n0+r)*DPAD + k0 + ko + 8];
        }
        __syncthreads();
        int kk = (lane >> 4) * 8;
        f16x8 a = *(const f16x8*)&As[wave*16 + (lane & 15)][kk];
#pragma unroll
        for (int nf = 0; nf < 8; ++nf) {
            f16x8 bfr = *(const f16x8*)&Bs[nf*16 + (lane & 15)][kk];
            acc[nf] = __builtin_amdgcn_mfma_f32_16x16x32_f16(a, bfr, acc[nf], 0, 0, 0);
        }
        __syncthreads();
    }
#pragma unroll
    for (int nf = 0; nf < 8; ++nf) {
        int n = n0 + nf*16 + (lane & 15);
        float bv = bih[n];
#pragma unroll
        for (int r = 0; r < 4; ++r) {
            int m = m0 + wave*16 + (lane >> 4)*4 + r;
            gx[(size_t)m*NW + n] = (_Float16)(acc[nf][r] + bv);
        }
    }
}

// ------------------ GRU recurrence: 128 blocks (b, dir) --------------------
// 512 threads: j = tid>>1, half = tid&1 (K-half), 192 dword weights/thread.
// __launch_bounds__(512, 1): min-waves/EU = 1 -> register budget 256/thread
// (the r1-r5 ladder showed grant = file/(2*waves_target): (512,2)->128).
// All 192 weight dwords live in PLAIN VGPRs: no AGPR pinning, no
// v_accvgpr_read (128/step saved), no asm constraint copy-chains (r10 ledger:
// ~470 phantom VALU instr/wave/step from register juggling around the asm).
// Demand ~247 <= 256; residency 2 waves/SIMD, 1 block/CU, zero spill.
__global__ void __launch_bounds__(512, 1)
gru_kernel(
        const float* __restrict__ whhf, const float* __restrict__ whhb,
        const float* __restrict__ bhhf, const float* __restrict__ bhhb,
        const _Float16* __restrict__ gx, _Float16* __restrict__ enc) {
    int bid = blockIdx.x;
    int dir = bid & 1, b = bid >> 1;
    int tid = threadIdx.x;
    int j = tid >> 1;
    int half = tid & 1;
    const float* whh = dir ? whhb : whhf;
    const float* bhh = dir ? bhhb : bhhf;

    // weight rows j (r), 256+j (z), 512+j (n); k in [half*128, half*128+128)
    unsigned wru[64], wzu[64], wnu[64];   // packed f16x2 dwords, plain VGPRs
    {
        const float2* pr = (const float2*)(whh + (size_t)j*HD        + half*128);
        const float2* pz = (const float2*)(whh + (size_t)(HD + j)*HD + half*128);
        const float2* pn = (const float2*)(whh + (size_t)(2*HD+j)*HD + half*128);
#pragma unroll
        for (int k = 0; k < 64; ++k) {
            float2 a = pr[k]; wru[k] = packh2(a.x, a.y);
            float2 c = pz[k]; wzu[k] = packh2(c.x, c.y);
            float2 d = pn[k]; wnu[k] = packh2(d.x, d.y);
        }
    }
    // bias folded into half==0 accumulator init
    float brh = half ? 0.f : bhh[j];
    float bzh = half ? 0.f : bhh[HD + j];
    float bnh = half ? 0.f : bhh[2*HD + j];

    // [dbuf][half][128 h + 8 pad] -> half stride 272 B (16B-aligned): the two
    // broadcast base addrs differ by 4 dword-banks -> conflict-free.
    __shared__ __align__(16) _Float16 hbuf[2][2][136];
    {
        _Float16* hz0 = &hbuf[0][0][0];
        if (tid < 2*2*136) hz0[tid] = (_Float16)0.f;
    }
    float hprev = 0.f;
    __syncthreads();

    const _Float16* gxb = gx + (size_t)b*T_SEQ*NW + dir*768 + j;
    int t = dir ? (T_SEQ - 1) : 0;
    int dt = dir ? -1 : 1;
    const _Float16* gp0 = gxb + (size_t)t*NW;
    float xr = (float)gp0[0], xz = (float)gp0[HD], xn = (float)gp0[2*HD];
    int cur = 0;

    for (int s = 0; s < T_SEQ; ++s) {
        // prefetch next step's gx; waitcnt lands after the dot loop
        float nxr = 0.f, nxz = 0.f, nxn = 0.f;
        if (s + 1 < T_SEQ) {
            const _Float16* gq = gxb + (size_t)(t + dt)*NW;
            nxr = (float)gq[0]; nxz = (float)gq[HD]; nxn = (float)gq[2*HD];
        }

        float ar = brh, az = bzh, an = bnh;
        float ar1 = 0.f, az1 = 0.f, an1 = 0.f;
        const uint4* hseg4 = (const uint4*)&hbuf[cur][half][0];
#pragma unroll
        for (int k8 = 0; k8 < 16; ++k8) {
            uint4 hv = hseg4[k8];
            ar  = dot2u(hv.x, wru[4*k8+0], ar);  ar1 = dot2u(hv.y, wru[4*k8+1], ar1);
            ar  = dot2u(hv.z, wru[4*k8+2], ar);  ar1 = dot2u(hv.w, wru[4*k8+3], ar1);
            az  = dot2u(hv.x, wzu[4*k8+0], az);  az1 = dot2u(hv.y, wzu[4*k8+1], az1);
            az  = dot2u(hv.z, wzu[4*k8+2], az);  az1 = dot2u(hv.w, wzu[4*k8+3], az1);
            an  = dot2u(hv.x, wnu[4*k8+0], an);  an1 = dot2u(hv.y, wnu[4*k8+1], an1);
            an  = dot2u(hv.z, wnu[4*k8+2], an);  an1 = dot2u(hv.w, wnu[4*k8+3], an1);
        }
        float hr = ar + ar1, hz = az + az1, hn = an + an1;
        // combine the two K-halves (pair lanes 2j, 2j+1 -- same wave)
        hr += __shfl_xor(hr, 1);
        hz += __shfl_xor(hz, 1);
        hn += __shfl_xor(hn, 1);

        float r  = sigmoidf_(xr + hr);
        float z  = sigmoidf_(xz + hz);
        float nn = tanhf_(xn + r * hn);
        float h  = (1.f - z) * nn + z * hprev;   // identical in both half lanes
        hprev = h;

        // packed h2 writes (dword granularity, conflict-free): thread with
        // (tid&3)==0 packs {h_j, h_{j+1}} via its xor-2 partner
        float hpar = __shfl_xor(h, 2);
        if ((tid & 3) == 0) {
            unsigned hp = packh2(h, hpar);
            *(unsigned*)&hbuf[cur ^ 1][j >> 7][j & 127] = hp;
            *(unsigned*)&enc[((size_t)(b*T_SEQ + t))*512 + dir*HD + j] = hp;
        }
        __syncthreads();
        xr = nxr; xz = nxz; xn = nxn;
        cur ^= 1; t += dt;
    }
}

// ------ GEMM U + fused tanh/ctx epilogue -> logits[ROWS]  (f16 MFMA) -------
__global__ __launch_bounds__(256) void gemm_u(const _Float16* __restrict__ enc,
                                              const _Float16* __restrict__ attwh,
                                              const float* __restrict__ attb,
                                              const float* __restrict__ ctx,
                                              float* __restrict__ logits) {
    int m0 = blockIdx.x * 64;
    __shared__ _Float16 As[64][40];
    __shared__ _Float16 Bs[512][40];
    int tid = threadIdx.x;
    int wave = tid >> 6, lane = tid & 63;
    f32x4 acc[32] = {};
    for (int kt = 0; kt < 16; ++kt) {
        int k0 = kt * 32;
        { // stage A (64 x 32)
            int r = tid >> 2, ko = (tid & 3) * 8;
            *(f16x8*)&As[r][ko] = *(const f16x8*)&enc[(size_t)(m0+r)*512 + k0 + ko];
        }
        { // stage B as [n][k] (512 x 32)
#pragma unroll
            for (int jr = 0; jr < 2; ++jr) {
                int row = tid*2 + jr;
#pragma unroll
                for (int q = 0; q < 4; ++q)
                    *(f16x8*)&Bs[row][q*8] =
                        *(const f16x8*)&attwh[(size_t)row*512 + k0 + q*8];
            }
        }
        __syncthreads();
        int kk = (lane >> 4) * 8;
        f16x8 a = *(const f16x8*)&As[wave*16 + (lane & 15)][kk];
#pragma unroll
        for (int nf = 0; nf < 32; ++nf) {
            f16x8 bfr = *(const f16x8*)&Bs[nf*16 + (lane & 15)][kk];
            acc[nf] = __builtin_amdgcn_mfma_f32_16x16x32_f16(a, bfr, acc[nf], 0, 0, 0);
        }
        __syncthreads();
    }
    // epilogue: tanh(u + b) . ctx, reduce over n
    float rs0 = 0.f, rs1 = 0.f, rs2 = 0.f, rs3 = 0.f;
#pragma unroll
    for (int nf = 0; nf < 32; ++nf) {
        int n = nf*16 + (lane & 15);
        float bv = attb[n], cv = ctx[n];
        rs0 += tanhf_(acc[nf][0] + bv) * cv;
        rs1 += tanhf_(acc[nf][1] + bv) * cv;
        rs2 += tanhf_(acc[nf][2] + bv) * cv;
        rs3 += tanhf_(acc[nf][3] + bv) * cv;
    }
#pragma unroll
    for (int off = 1; off < 16; off <<= 1) {
        rs0 += __shfl_xor(rs0, off);
        rs1 += __shfl_xor(rs1, off);
        rs2 += __shfl_xor(rs2, off);
        rs3 += __shfl_xor(rs3, off);
    }
    if ((lane & 15) == 0) {
        int mb = m0 + wave*16 + (lane >> 4)*4;
        logits[mb + 0] = rs0;
        logits[mb + 1] = rs1;
        logits[mb + 2] = rs2;
        logits[mb + 3] = rs3;
    }
}

// ---------------- masked softmax over T + weighted pooling -----------------
__global__ __launch_bounds__(256) void softmax_pool(const float* __restrict__ logits,
                                                    const _Float16* __restrict__ enc,
                                                    const int* __restrict__ lengths,
                                                    float* __restrict__ out) {
    int b = blockIdx.x, tid = threadIdx.x;
    int len = lengths[b];
    if (len < 1) len = 1;
    if (len > T_SEQ) len = T_SEQ;
    __shared__ float att[T_SEQ];
    __shared__ float red[8];
    const float* lg = logits + (size_t)b*T_SEQ;

    float m = -1e30f;
    for (int t = tid; t < len; t += 256) m = fmaxf(m, lg[t]);
#pragma unroll
    for (int off = 1; off < 64; off <<= 1) m = fmaxf(m, __shfl_xor(m, off));
    if ((tid & 63) == 0) red[tid >> 6] = m;
    __syncthreads();
    m = fmaxf(fmaxf(red[0], red[1]), fmaxf(red[2], red[3]));

    float s = 0.f;
    for (int t = tid; t < len; t += 256) {
        float e = __expf(lg[t] - m);
        att[t] = e;
        s += e;
    }
#pragma unroll
    for (int off = 1; off < 64; off <<= 1) s += __shfl_xor(s, off);
    if ((tid & 63) == 0) red[4 + (tid >> 6)] = s;
    __syncthreads();
    s = red[4] + red[5] + red[6] + red[7];
    float inv = 1.f / s;

    float a0 = 0.f, a1 = 0.f;
    const _Float16* eb = enc + (size_t)b*T_SEQ*512;
    for (int t = 0; t < len; ++t) {
        float w = att[t];
        a0 += w * (float)eb[(size_t)t*512 + tid];
        a1 += w * (float)eb[(size_t)t*512 + 256 + tid];
    }
    out[(size_t)b*512 + tid]       = a0 * inv;
    out[(size_t)b*512 + 256 + tid] = a1 * inv;
}

extern "C" void kernel_launch(void* const* d_in, const int* in_sizes, int n_in,
                              void* d_out, int out_size, void* d_ws, size_t ws_size,
                              hipStream_t stream) {
    const float* x    = (const float*)d_in[0];
    const int*   len  = (const int*)  d_in[1];
    const float* wihf = (const float*)d_in[2];
    const float* whhf = (const float*)d_in[3];
    const float* bihf = (const float*)d_in[4];
    const float* bhhf = (const float*)d_in[5];
    const float* wihb = (const float*)d_in[6];
    const float* whhb = (const float*)d_in[7];
    const float* bihb = (const float*)d_in[8];
    const float* bhhb = (const float*)d_in[9];
    const float* attw = (const float*)d_in[10];
    const float* attb = (const float*)d_in[11];
    const float* ctxv = (const float*)d_in[12];
    float* out = (float*)d_out;

    char* ws = (char*)d_ws;
    size_t off = 0;
    _Float16* xh    = (_Float16*)(ws + off); off += (size_t)ROWS*DPAD*2;
    _Float16* wih   = (_Float16*)(ws + off); off += (size_t)NW*DPAD*2;
    _Float16* attwh = (_Float16*)(ws + off); off += (size_t)512*512*2;
    float*    bih   = (float*)   (ws + off); off += (size_t)NW*4;
    _Float16* gx    = (_Float16*)(ws + off); off += (size_t)ROWS*NW*2;
    _Float16* enc   = (_Float16*)(ws + off); off += (size_t)ROWS*512*2;
    float*    logit = (float*)   (ws + off); off += (size_t)ROWS*4;

    prep_x<<<dim3(ROWS), dim3(DPAD), 0, stream>>>(x, len, xh);
    prep_w<<<dim3(NW + 512), dim3(512), 0, stream>>>(wihf, wihb, bihf, bihb, attw,
                                                     wih, attwh, bih);
    gemm_gx<<<dim3(ROWS/64, NW/128), dim3(256), 0, stream>>>(xh, wih, bih, gx);
    gru_kernel<<<dim3(2*BATCH), dim3(512), 0, stream>>>(whhf, whhb, bhhf, bhhb, gx, enc);
    gemm_u<<<dim3(ROWS/64), dim3(256), 0, stream>>>(enc, attwh, attb, ctxv, logit);
    softmax_pool<<<dim3(BATCH), dim3(256), 0, stream>>>(logit, enc, len, out);
}